// Round 17
// baseline (1734.740 us; speedup 1.0000x reference)
//
#include <hip/hip_runtime.h>
#include <math.h>

// Problem constants
#define NB 64      // batch
#define NS 128     // seq len
#define ND 1024    // input dim
#define NH 512     // hidden
#define NG 2048    // 4*H
#define NTOT 255   // 2S-1
#define NSTEPS 127 // S-1
#define NWV 511
#define NPV 152

static const size_t XPB_SZ = (size_t)2 * NS * NG * NB;
static const size_t H_SZ   = (size_t)2 * NS * NH * NB;   // region reused: vecp_bf + wp_bf
static const size_t VEC_SZ = (size_t)NB * NTOT * NH;
static const size_t HB_SZ  = (size_t)2 * NS * NH * NB;
static const size_t EB_SZ  = (size_t)NB * NS * ND;
static const size_t WB_SZ  = (size_t)4096 * ND;
static const size_t W12_SZ = (size_t)2 * NH * NH;        // 524288
static const size_t WO_SZ  = (size_t)512 * NH;           // 262144 (511 rows + pad)
static const size_t VB_SZ  = (size_t)NB * NS * NH;       // 4194304
static const size_t VP_SZ  = (size_t)8192 * NH;          // 4194304 (8128 + pad)
static const size_t WP_SZ  = (size_t)256 * NH;           // 131072 (152 + pad)
// flag-array barrier allocation (generous): 127*2*32 slots x 32-int padding
#define BAR_TOT (127 * 2 * 32 * 32)

typedef __attribute__((ext_vector_type(8))) short short8v;
typedef __attribute__((ext_vector_type(8))) unsigned short ushort8v;
typedef __attribute__((ext_vector_type(4))) float float4v;

__device__ __forceinline__ float sigm(float x) { return 1.f / (1.f + __expf(-x)); }
__device__ __forceinline__ float tanh_fast(float x) {
  const float e = __expf(2.f * x);
  return 1.f - 2.f / (e + 1.f);
}
__device__ __forceinline__ unsigned short f2bf(float x) {
  unsigned b = __float_as_uint(x);
  return (unsigned short)((b + 0x7FFFu + ((b >> 16) & 1u)) >> 16);
}
__device__ __forceinline__ float bf2f(unsigned short u) {
  return __uint_as_float(((unsigned)u) << 16);
}

// ---------------- K0: fp32 -> bf16 conversions + barrier zero -------------
__global__ __launch_bounds__(256) void k_cvt(
    const float* __restrict__ elmo, const float* __restrict__ wf,
    const float* __restrict__ wb, const float* __restrict__ W1,
    const float* __restrict__ W2, const float* __restrict__ wordW,
    const float* __restrict__ phraseW,
    unsigned short* __restrict__ elmo_bf, unsigned short* __restrict__ W_bf,
    unsigned short* __restrict__ W12_bf, unsigned short* __restrict__ wout_bf,
    unsigned short* __restrict__ wp_bf, int* __restrict__ bar) {
  const int gid = blockIdx.x * 256 + threadIdx.x;
  if (gid < BAR_TOT) bar[gid] = 0;
  const int NE4 = (NB * NS * ND) / 4;   // 2,097,152
  const int NW4 = (4096 * ND) / 4;      // 1,048,576
  const int NW4h = NW4 / 2;
  const int N12 = (int)(W12_SZ / 4);    // 131,072
  const int NWO = (int)(WO_SZ / 4);     // 65,536
  const int NWO_real = (NWV * NH) / 4;  // 65,408
  const int NP4 = (int)(WP_SZ / 4);     // 32,768
  const int NP4_real = (NPV * NH) / 4;  // 19,456
  const int TOT = NE4 + NW4 + N12 + NWO + NP4;
  for (int i = gid; i < TOT; i += gridDim.x * 256) {
    float4 v = make_float4(0.f, 0.f, 0.f, 0.f);
    unsigned short* dst;
    if (i < NE4) {
      const int e0 = i << 2;
      const int b = e0 >> 17;
      const int t = (e0 >> 10) & 127;
      const int k = e0 & 1023;
      v = *(const float4*)(elmo + e0);
      dst = elmo_bf + ((size_t)((t << 6) + b) << 10) + k;
    } else if (i < NE4 + NW4) {
      const int j = i - NE4;
      v = (j < NW4h) ? *(const float4*)(wf + ((size_t)j << 2))
                     : *(const float4*)(wb + ((size_t)(j - NW4h) << 2));
      dst = W_bf + ((size_t)j << 2);
    } else if (i < NE4 + NW4 + N12) {
      const int j = i - NE4 - NW4;
      const int half = N12 / 2;
      v = (j < half) ? *(const float4*)(W1 + ((size_t)j << 2))
                     : *(const float4*)(W2 + ((size_t)(j - half) << 2));
      dst = W12_bf + ((size_t)j << 2);
    } else if (i < NE4 + NW4 + N12 + NWO) {
      const int j = i - NE4 - NW4 - N12;
      if (j < NWO_real) v = *(const float4*)(wordW + ((size_t)j << 2));
      dst = wout_bf + ((size_t)j << 2);
    } else {
      const int j = i - NE4 - NW4 - N12 - NWO;
      if (j < NP4_real) v = *(const float4*)(phraseW + ((size_t)j << 2));
      dst = wp_bf + ((size_t)j << 2);
    }
    uint2 u;
    u.x = (unsigned)f2bf(v.x) | ((unsigned)f2bf(v.y) << 16);
    u.y = (unsigned)f2bf(v.z) | ((unsigned)f2bf(v.w) << 16);
    *(uint2*)dst = u;
  }
}

// ---------------- K1: xp = elmo @ w_ih^T + bias (bf16 MFMA) ---------------
__global__ __launch_bounds__(256) void k_xp(
    const unsigned short* __restrict__ elmo_bf,
    const unsigned short* __restrict__ W_bf,
    const float* __restrict__ biasf, const float* __restrict__ biasb,
    unsigned short* __restrict__ xpb) {
  __shared__ unsigned short As[128 * 64];
  __shared__ unsigned short Bs[128 * 64];
  const int tid = threadIdx.x;
  const int n0 = blockIdx.x * 128;
  const int m0 = blockIdx.y * 128;
  const int wv = tid >> 6, lane = tid & 63;
  const int cl = lane & 15, bq = lane >> 4;
  const int wm = (wv >> 1) << 6;
  const int wn = (wv & 1) << 6;
  const int sr = tid >> 1, skc = (tid & 1) << 5;
  const unsigned short* asrc = elmo_bf + (size_t)(m0 + sr) * ND + skc;
  const unsigned short* bsrc = W_bf + (size_t)(n0 + sr) * ND + skc;
  const int sswz = (sr & 15) << 3;
  float4v acc[4][4];
#pragma unroll
  for (int nt = 0; nt < 4; ++nt) {
    const int n = n0 + wn + nt * 16 + cl;
    const float bv = (n < 2048) ? biasf[n] : biasb[n - 2048];
#pragma unroll
    for (int mt = 0; mt < 4; ++mt) acc[mt][nt] = (float4v){bv, bv, bv, bv};
  }
  for (int k0 = 0; k0 < ND; k0 += 64) {
    ushort8v av4[4], bv4[4];
#pragma unroll
    for (int i = 0; i < 4; ++i) av4[i] = *(const ushort8v*)(asrc + k0 + 8 * i);
#pragma unroll
    for (int i = 0; i < 4; ++i) bv4[i] = *(const ushort8v*)(bsrc + k0 + 8 * i);
    __syncthreads();
#pragma unroll
    for (int i = 0; i < 4; ++i) {
      *(ushort8v*)&As[((sr << 6) + skc + 8 * i) ^ sswz] = av4[i];
      *(ushort8v*)&Bs[((sr << 6) + skc + 8 * i) ^ sswz] = bv4[i];
    }
    __syncthreads();
#pragma unroll
    for (int ks = 0; ks < 2; ++ks) {
      const int koff = (ks << 5) + (bq << 3);
      short8v af[4], bf_[4];
#pragma unroll
      for (int mt = 0; mt < 4; ++mt) {
        const int ar = wm + mt * 16 + cl;
        af[mt] = *(const short8v*)&As[((ar << 6) + koff) ^ ((ar & 15) << 3)];
      }
#pragma unroll
      for (int nt = 0; nt < 4; ++nt) {
        const int br = wn + nt * 16 + cl;
        bf_[nt] = *(const short8v*)&Bs[((br << 6) + koff) ^ ((br & 15) << 3)];
      }
#pragma unroll
      for (int mt = 0; mt < 4; ++mt)
#pragma unroll
        for (int nt = 0; nt < 4; ++nt)
          acc[mt][nt] =
              __builtin_amdgcn_mfma_f32_16x16x32_bf16(af[mt], bf_[nt], acc[mt][nt], 0, 0, 0);
    }
  }
#pragma unroll
  for (int mt = 0; mt < 4; ++mt) {
    const int mbase = m0 + wm + mt * 16 + (bq << 2);
    const int t = mbase >> 6, b4 = mbase & 63;
#pragma unroll
    for (int nt = 0; nt < 4; ++nt) {
      const int n = n0 + wn + nt * 16 + cl;
      const int dir = n >> 11, grow = n & 2047;
      const int g = grow >> 9, cb = (grow & 511) >> 4;
      const float4v a = acc[mt][nt];
      uint2 u;
      u.x = (unsigned)f2bf(a[0]) | ((unsigned)f2bf(a[1]) << 16);
      u.y = (unsigned)f2bf(a[2]) | ((unsigned)f2bf(a[3]) << 16);
      const size_t idx =
          ((((size_t)(dir * NS + t) * 32 + cb) * 4 + g) << 10) + (cl << 6) + b4;
      *(uint2*)&xpb[idx] = u;
    }
  }
}

// ---------------- K2: persistent BiLSTM scan, v13 -------------------------
// 32 blocks = 2 dir x 16 col-blocks of 32 (HALVED barrier participants).
// W slice (4g x 32col x 512k bf16) = 128 KB LDS. Per wave: acc[8] = 8
// N-tiles (2 col-halves x 4 gates). A-frags direct from h_bf (v8 path).
// Each thread owns 2 cols x 4 b cells. 16-slot flag barrier.
__global__ __launch_bounds__(256) void k_lstm(
    const float* __restrict__ whh_f, const float* __restrict__ whh_b,
    const unsigned short* __restrict__ xpb,
    unsigned short* __restrict__ h_bf, int* __restrict__ bar) {
  __shared__ unsigned short WS[128 * 512];             // 128 KB, swizzled [gr][k]
  __shared__ __align__(16) unsigned short hOut[64 * 32];  // 4 KB [b][c]
  const int bid = blockIdx.x;
  const int dir = bid >> 4;
  const int cb = bid & 15;
  const int col0 = cb << 5;        // 32 cols per block
  const int tid = threadIdx.x;
  const int lane = tid & 63;
  const int w = tid >> 6;
  const int cl = lane & 15, bq = lane >> 4;
  const int b4 = (w << 4) + (bq << 2);
  const int arow = (w << 4) + cl;
  const float* whh = dir ? whh_b : whh_f;

  // one-time: W slice fp32 -> bf16 LDS. gr = tid>>1 (0..127 = g*32+c), k-half
  {
    const int gr = tid >> 1;
    const int kh = (tid & 1) << 8;
    const int g = gr >> 5, c = gr & 31;
    const float* src = whh + (size_t)(g * NH + col0 + c) * NH + kh;
    const int swz = (gr & 15) << 3;
#pragma unroll
    for (int i = 0; i < 32; ++i) {
      const float4 f0 = *(const float4*)(src + 8 * i);
      const float4 f1 = *(const float4*)(src + 8 * i + 4);
      ushort8v u;
      u[0] = f2bf(f0.x); u[1] = f2bf(f0.y); u[2] = f2bf(f0.z); u[3] = f2bf(f0.w);
      u[4] = f2bf(f1.x); u[5] = f2bf(f1.y); u[6] = f2bf(f1.z); u[7] = f2bf(f1.w);
      *(ushort8v*)&WS[((gr << 9) + kh + 8 * i) ^ swz] = u;
    }
  }
  __syncthreads();

  unsigned short* hb_us = h_bf + ((size_t)dir * NS << 15);      // [pos][b][k]
  unsigned long long* hb_ull = (unsigned long long*)h_bf + ((size_t)dir * NS << 12);

  float4v c4lo = {0.f, 0.f, 0.f, 0.f};
  float4v c4hi = {0.f, 0.f, 0.f, 0.f};

  for (int t = 0; t < NS; ++t) {
    const int pos = dir ? (NS - 1 - t) : t;
    // xp loads for both 16-col halves of this block's 32 cols
    const unsigned short* xcl =
        xpb + (((size_t)(dir * NS + pos) * 32 + (cb << 1)) << 12);
    const unsigned short* xch = xcl + 4096;
    uint2 xlo[4], xhi[4];
#pragma unroll
    for (int g = 0; g < 4; ++g) {
      xlo[g] = *(const uint2*)&xcl[(g << 10) + (cl << 6) + b4];
      xhi[g] = *(const uint2*)&xch[(g << 10) + (cl << 6) + b4];
    }
    float4v acc[8] = {{0.f,0.f,0.f,0.f},{0.f,0.f,0.f,0.f},{0.f,0.f,0.f,0.f},
                      {0.f,0.f,0.f,0.f},{0.f,0.f,0.f,0.f},{0.f,0.f,0.f,0.f},
                      {0.f,0.f,0.f,0.f},{0.f,0.f,0.f,0.f}};
    if (t > 0) {
      const int prevpos = dir ? (pos + 1) : (pos - 1);
      const unsigned long long* hsrc = hb_ull + ((size_t)prevpos << 13);
      unsigned long long ha0[16], ha1[16];
#pragma unroll
      for (int ks = 0; ks < 16; ++ks) {
        const int uidx = (arow << 7) + (ks << 3) + (bq << 1);
        ha0[ks] = __hip_atomic_load(&hsrc[uidx], __ATOMIC_RELAXED,
                                    __HIP_MEMORY_SCOPE_AGENT);
        ha1[ks] = __hip_atomic_load(&hsrc[uidx + 1], __ATOMIC_RELAXED,
                                    __HIP_MEMORY_SCOPE_AGENT);
      }
#pragma unroll
      for (int ks = 0; ks < 16; ++ks) {
        union { unsigned long long u[2]; short8v v; } au;
        au.u[0] = ha0[ks]; au.u[1] = ha1[ks];
        const short8v a = au.v;
        const int koff = (ks << 5) + (bq << 3);
#pragma unroll
        for (int nt = 0; nt < 8; ++nt) {
          const int grb = (nt << 4) + cl;
          const short8v bb =
              *(const short8v*)&WS[((grb << 9) + koff) ^ (cl << 3)];
          acc[nt] = __builtin_amdgcn_mfma_f32_16x16x32_bf16(a, bb, acc[nt], 0, 0, 0);
        }
      }
    }
    // cell update: thread owns cols (col0+cl) and (col0+cl+16), b4..b4+3
    // lo col: gates = acc[0,2,4,6]; hi col: acc[1,3,5,7]
#pragma unroll
    for (int i = 0; i < 4; ++i) {
      const int sh = (i & 1) << 4;
      {
        const unsigned x0 = (i < 2) ? xlo[0].x : xlo[0].y;
        const unsigned x1 = (i < 2) ? xlo[1].x : xlo[1].y;
        const unsigned x2 = (i < 2) ? xlo[2].x : xlo[2].y;
        const unsigned x3 = (i < 2) ? xlo[3].x : xlo[3].y;
        const float gi = sigm(acc[0][i] + bf2f((unsigned short)(x0 >> sh)));
        const float gf = sigm(acc[2][i] + bf2f((unsigned short)(x1 >> sh)));
        const float gc = tanh_fast(acc[4][i] + bf2f((unsigned short)(x2 >> sh)));
        const float go = sigm(acc[6][i] + bf2f((unsigned short)(x3 >> sh)));
        c4lo[i] = gf * c4lo[i] + gi * gc;
        hOut[((b4 + i) << 5) + cl] = f2bf(go * tanh_fast(c4lo[i]));
      }
      {
        const unsigned x0 = (i < 2) ? xhi[0].x : xhi[0].y;
        const unsigned x1 = (i < 2) ? xhi[1].x : xhi[1].y;
        const unsigned x2 = (i < 2) ? xhi[2].x : xhi[2].y;
        const unsigned x3 = (i < 2) ? xhi[3].x : xhi[3].y;
        const float gi = sigm(acc[1][i] + bf2f((unsigned short)(x0 >> sh)));
        const float gf = sigm(acc[3][i] + bf2f((unsigned short)(x1 >> sh)));
        const float gc = tanh_fast(acc[5][i] + bf2f((unsigned short)(x2 >> sh)));
        const float go = sigm(acc[7][i] + bf2f((unsigned short)(x3 >> sh)));
        c4hi[i] = gf * c4hi[i] + gi * gc;
        hOut[((b4 + i) << 5) + cl + 16] = f2bf(go * tanh_fast(c4hi[i]));
      }
    }
    __syncthreads();  // hOut visible
    // FULL-coverage packed exchange: 256 thr x 16B (4KB = 64 b x 32 col)
    {
      const int bb = tid >> 2, q = tid & 3;
      const unsigned long long* src =
          (const unsigned long long*)&hOut[(bb << 5) + (q << 3)];
      const unsigned long long v0 = src[0];
      const unsigned long long v1 = src[1];
      unsigned long long* dst = (unsigned long long*)&hb_us[
          ((size_t)pos << 15) + (bb << 9) + col0 + (q << 3)];
      __hip_atomic_store(&dst[0], v0, __ATOMIC_RELAXED, __HIP_MEMORY_SCOPE_AGENT);
      __hip_atomic_store(&dst[1], v1, __ATOMIC_RELAXED, __HIP_MEMORY_SCOPE_AGENT);
    }
    if (t < NS - 1) {
      __syncthreads();  // drains h stores before the flag (release order)
      const int fbase = (((t << 1) + dir) << 4);
      if (tid == 0) {
        __hip_atomic_store(&bar[(size_t)(fbase + cb) << 5], 1,
                           __ATOMIC_RELAXED, __HIP_MEMORY_SCOPE_AGENT);
      }
      if (tid < 64) {
        while (true) {
          int v = 1;
          if (lane < 16)
            v = __hip_atomic_load(&bar[(size_t)(fbase + lane) << 5],
                                  __ATOMIC_RELAXED, __HIP_MEMORY_SCOPE_AGENT);
          if (__all(v != 0)) break;
        }
      }
      __syncthreads();
    }
  }
}

// ---------------- K3: combined = lrelu(fwd@W1^T + bwd@W2^T), bf16 MFMA ----
__global__ __launch_bounds__(256) void k_comb(
    const unsigned short* __restrict__ h_bf,
    const unsigned short* __restrict__ W12_bf, float* __restrict__ vec) {
  __shared__ unsigned short A1s[64 * 128], A2s[64 * 128];
  __shared__ unsigned short B1s[64 * 128], B2s[64 * 128];
  const int tid = threadIdx.x;
  const int n0 = blockIdx.x * 64;
  const int s = blockIdx.y;
  const int w = tid >> 6, lane = tid & 63;
  const int cl = lane & 15, bq = lane >> 4;
  const int wn = w << 4;
  const unsigned short* a1src = h_bf + ((size_t)s << 15);
  const unsigned short* a2src = h_bf + ((size_t)(NS + s) << 15);
  const unsigned short* b1src = W12_bf + (size_t)n0 * NH;
  const unsigned short* b2src = W12_bf + (size_t)(NH + n0) * NH;
  const int srow = tid >> 2, skq = (tid & 3) << 5;
  const int sswz = (srow & 15) << 3;
  float4v acc[4] = {{0.f, 0.f, 0.f, 0.f}, {0.f, 0.f, 0.f, 0.f},
                    {0.f, 0.f, 0.f, 0.f}, {0.f, 0.f, 0.f, 0.f}};
  for (int k0 = 0; k0 < NH; k0 += 128) {
    ushort8v a1[4], a2[4], b1[4], b2[4];
#pragma unroll
    for (int i = 0; i < 4; ++i) {
      const size_t off = (size_t)srow * NH + k0 + skq + 8 * i;
      a1[i] = *(const ushort8v*)(a1src + off);
      a2[i] = *(const ushort8v*)(a2src + off);
      b1[i] = *(const ushort8v*)(b1src + off);
      b2[i] = *(const ushort8v*)(b2src + off);
    }
    __syncthreads();
#pragma unroll
    for (int i = 0; i < 4; ++i) {
      const int idx = ((srow << 7) + skq + 8 * i) ^ sswz;
      *(ushort8v*)&A1s[idx] = a1[i];
      *(ushort8v*)&A2s[idx] = a2[i];
      *(ushort8v*)&B1s[idx] = b1[i];
      *(ushort8v*)&B2s[idx] = b2[i];
    }
    __syncthreads();
#pragma unroll
    for (int ks = 0; ks < 4; ++ks) {
      const int koff = (ks << 5) + (bq << 3);
      const short8v bf1 =
          *(const short8v*)&B1s[(((wn + cl) << 7) + koff) ^ (cl << 3)];
      const short8v bf2 =
          *(const short8v*)&B2s[(((wn + cl) << 7) + koff) ^ (cl << 3)];
#pragma unroll
      for (int mt = 0; mt < 4; ++mt) {
        const int ar = mt * 16 + cl;
        const short8v af1 = *(const short8v*)&A1s[((ar << 7) + koff) ^ (cl << 3)];
        const short8v af2 = *(const short8v*)&A2s[((ar << 7) + koff) ^ (cl << 3)];
        acc[mt] = __builtin_amdgcn_mfma_f32_16x16x32_bf16(af1, bf1, acc[mt], 0, 0, 0);
        acc[mt] = __builtin_amdgcn_mfma_f32_16x16x32_bf16(af2, bf2, acc[mt], 0, 0, 0);
      }
    }
  }
  const int n = n0 + wn + cl;
#pragma unroll
  for (int mt = 0; mt < 4; ++mt) {
    const int b0 = mt * 16 + (bq << 2);
#pragma unroll
    for (int i = 0; i < 4; ++i) {
      float v = acc[mt][i];
      v = v > 0.f ? v : 0.01f * v;
      vec[((size_t)(b0 + i) * NTOT + s) * NH + n] = v;
    }
  }
}

// ---------------- K4: l2-normalize word rows; emit fp32 + bf16 ------------
__global__ __launch_bounds__(256) void k_norm(float* __restrict__ vec,
                                              unsigned short* __restrict__ vec_bf) {
  const int row = (blockIdx.x << 2) + (threadIdx.x >> 6);  // 0..8191
  const int lane = threadIdx.x & 63;
  const int b = row >> 7, s = row & 127;
  float* p = vec + ((size_t)b * NTOT + s) * NH;
  float4 v0 = *(float4*)(p + (lane << 3));
  float4 v1 = *(float4*)(p + (lane << 3) + 4);
  float ss = v0.x * v0.x + v0.y * v0.y + v0.z * v0.z + v0.w * v0.w +
             v1.x * v1.x + v1.y * v1.y + v1.z * v1.z + v1.w * v1.w;
#pragma unroll
  for (int off = 32; off; off >>= 1) ss += __shfl_down(ss, off);
  ss = __shfl(ss, 0);
  const float sc = 1.f / fmaxf(sqrtf(ss), 1e-12f);
  v0.x *= sc; v0.y *= sc; v0.z *= sc; v0.w *= sc;
  v1.x *= sc; v1.y *= sc; v1.z *= sc; v1.w *= sc;
  *(float4*)(p + (lane << 3)) = v0;
  *(float4*)(p + (lane << 3) + 4) = v1;
  ushort8v u;
  u[0] = f2bf(v0.x); u[1] = f2bf(v0.y); u[2] = f2bf(v0.z); u[3] = f2bf(v0.w);
  u[4] = f2bf(v1.x); u[5] = f2bf(v1.y); u[6] = f2bf(v1.z); u[7] = f2bf(v1.w);
  *(ushort8v*)&vec_bf[((size_t)row << 9) + (lane << 3)] = u;
}

// ---------------- K5: fused tail: compose (64) | word GEMM (256) | labels -
// compose v4: sliding-window register rotation (rvd reads per 4-j chunk
// 3 -> 1; LDS traffic on the single-CU critical path ~halved).
#define SKW(f) ((f) + (((f) >> 5) << 2))
__global__ __launch_bounds__(512) void k_tail(
    float* __restrict__ vec, const int* __restrict__ cinfo,
    unsigned short* __restrict__ vecp_bf,
    const unsigned short* __restrict__ vec_bf,
    const unsigned short* __restrict__ wout_bf,
    const float* __restrict__ wbias, float* __restrict__ out_word,
    const int* __restrict__ lab, float* __restrict__ out_lw,
    float* __restrict__ out_lp) {
  __shared__ float lv[512];
  __shared__ float rvd[1152];
  __shared__ float cpart[8 * 576];
  __shared__ float red[8];
  __shared__ int ciS[NSTEPS * 4];
  __shared__ unsigned short As[128 * 64];
  __shared__ unsigned short Bs[128 * 64];
  const int bid = blockIdx.x;
  const int tid = threadIdx.x;

  if (bid < 64) {
    // ---------------- compose ----------------
    const int b = bid;
    float* vb = vec + (size_t)b * NTOT * NH;
    const int* ib = cinfo + b * NSTEPS * 4;
    for (int idx = tid; idx < NSTEPS * 4; idx += 512) ciS[idx] = ib[idx];
    const int jq = tid >> 6;
    const int jb = jq << 6;
    const int k8 = (tid & 63) << 3;
    const int wid = tid >> 6, lane = tid & 63;
    __syncthreads();
    int p = ciS[1];
    float lvv = vb[(size_t)ciS[2] * NH + tid];
    float rvv = vb[(size_t)ciS[3] * NH + tid];
    for (int i = 0; i < NSTEPS; ++i) {
      lv[tid] = lvv;
      rvd[SKW(tid)] = rvv;
      rvd[SKW(512 + tid)] = rvv;
      __syncthreads();
      float acc[8] = {};
      float4 r0 = *(const float4*)&rvd[SKW(jb + k8)];
      float4 r1 = *(const float4*)&rvd[SKW(jb + k8 + 4)];
#pragma unroll 4
      for (int jj = 0; jj < 64; jj += 4) {
        const int j = jb + jj;
        const float4 l4 = *(const float4*)&lv[j];
        const float4 r2 = *(const float4*)&rvd[SKW(j + k8 + 8)];
        const float rw[12] = {r0.x, r0.y, r0.z, r0.w, r1.x, r1.y,
                              r1.z, r1.w, r2.x, r2.y, r2.z, r2.w};
#pragma unroll
        for (int kk = 0; kk < 8; ++kk)
          acc[kk] += l4.x * rw[kk] + l4.y * rw[kk + 1] + l4.z * rw[kk + 2] +
                     l4.w * rw[kk + 3];
        r0 = r1; r1 = r2;
      }
      const int ca = jq * 576 + SKW(k8);
      *(float4*)&cpart[ca] = make_float4(acc[0], acc[1], acc[2], acc[3]);
      *(float4*)&cpart[ca + 4] = make_float4(acc[4], acc[5], acc[6], acc[7]);
      __syncthreads();
      int pn = 0, ln = 0, rn = 0;
      float lf = 0.f, rf = 0.f;
      const bool more = (i + 1 < NSTEPS);
      if (more) {
        pn = ciS[(i + 1) * 4 + 1];
        ln = ciS[(i + 1) * 4 + 2];
        rn = ciS[(i + 1) * 4 + 3];
        lf = vb[(size_t)ln * NH + tid];
        rf = vb[(size_t)rn * NH + tid];
      }
      float ck = 0.f;
      const int ra = SKW(tid);
#pragma unroll
      for (int q = 0; q < 8; ++q) ck += cpart[q * 576 + ra];
      float ss = ck * ck;
#pragma unroll
      for (int off = 32; off; off >>= 1) ss += __shfl_xor(ss, off);
      if (lane == 0) red[wid] = ss;
      __syncthreads();
      const float tot = red[0] + red[1] + red[2] + red[3] +
                        red[4] + red[5] + red[6] + red[7];
      const float inv = 1.f / fmaxf(sqrtf(tot), 1e-12f);
      const float written = ck * inv;
      vb[(size_t)p * NH + tid] = written;
      vecp_bf[((size_t)b * 127 + (p - NS)) * NH + tid] = f2bf(written);
      if (more) {
        lvv = (ln == p) ? written : lf;
        rvv = (rn == p) ? written : rf;
        p = pn;
      }
      __syncthreads();
    }
  } else if (bid < 320) {
    // ---------------- word output GEMM (512-thread) ----------------
    const int obid = bid - 64;
    const int n0 = (obid & 3) * 128;
    const int m0 = (obid >> 2) * 128;
    const int wv = tid >> 6, lane = tid & 63;
    const int cl = lane & 15, bq = lane >> 4;
    const int wm = (wv >> 2) << 6;
    const int wn = ((wv >> 1) & 1) << 6;
    const int mts = (wv & 1) << 1;   // mt base: 0 or 2
    const int sr = tid >> 2, skc = (tid & 3) << 4;
    const unsigned short* asrc = vec_bf + (size_t)(m0 + sr) * NH + skc;
    const unsigned short* bsrc = wout_bf + (size_t)(n0 + sr) * NH + skc;
    const int sswz = (sr & 15) << 3;
    float4v acc[2][4] = {};
    for (int k0 = 0; k0 < NH; k0 += 64) {
      ushort8v av4[2], bv4[2];
#pragma unroll
      for (int i = 0; i < 2; ++i) av4[i] = *(const ushort8v*)(asrc + k0 + 8 * i);
#pragma unroll
      for (int i = 0; i < 2; ++i) bv4[i] = *(const ushort8v*)(bsrc + k0 + 8 * i);
      __syncthreads();
#pragma unroll
      for (int i = 0; i < 2; ++i) {
        *(ushort8v*)&As[((sr << 6) + skc + 8 * i) ^ sswz] = av4[i];
        *(ushort8v*)&Bs[((sr << 6) + skc + 8 * i) ^ sswz] = bv4[i];
      }
      __syncthreads();
#pragma unroll
      for (int ks = 0; ks < 2; ++ks) {
        const int koff = (ks << 5) + (bq << 3);
        short8v af[2], bf_[4];
#pragma unroll
        for (int mtl = 0; mtl < 2; ++mtl) {
          const int ar = wm + (mts + mtl) * 16 + cl;
          af[mtl] = *(const short8v*)&As[((ar << 6) + koff) ^ ((ar & 15) << 3)];
        }
#pragma unroll
        for (int nt = 0; nt < 4; ++nt) {
          const int br = wn + nt * 16 + cl;
          bf_[nt] = *(const short8v*)&Bs[((br << 6) + koff) ^ ((br & 15) << 3)];
        }
#pragma unroll
        for (int mtl = 0; mtl < 2; ++mtl)
#pragma unroll
          for (int nt = 0; nt < 4; ++nt)
            acc[mtl][nt] = __builtin_amdgcn_mfma_f32_16x16x32_bf16(
                af[mtl], bf_[nt], acc[mtl][nt], 0, 0, 0);
      }
    }
#pragma unroll
    for (int mtl = 0; mtl < 2; ++mtl) {
      const int mb = m0 + wm + (mts + mtl) * 16 + (bq << 2);
#pragma unroll
      for (int nt = 0; nt < 4; ++nt) {
        const int n = n0 + wn + nt * 16 + cl;
        if (n < NWV) {
          const float bn = wbias[n];
#pragma unroll
          for (int i = 0; i < 4; ++i)
            out_word[(size_t)(mb + i) * NWV + n] = acc[mtl][nt][i] + bn;
        }
      }
    }
  } else {
    // ---------------- labels ----------------
    const int i = (bid - 320) * 512 + tid;
    if (i < NB * NS) {
      const int b = i >> 7, s = i & 127;
      out_lw[i] = (float)lab[b * NTOT + s];
    }
    if (i < NB * NSTEPS) {
      const int b = i / 127;
      out_lp[i] = (float)lab[b * NTOT + NS + (i - b * 127)];
    }
  }
}

// ---------------- K6b: phrase output GEMM, bf16 MFMA ----------------------
__global__ __launch_bounds__(256) void k_outp(
    const unsigned short* __restrict__ vecp_bf,
    const unsigned short* __restrict__ wp_bf,
    const float* __restrict__ bias, float* __restrict__ out) {
  __shared__ unsigned short As[128 * 64];
  __shared__ unsigned short Bs[128 * 64];
  const int tid = threadIdx.x;
  const int n0 = blockIdx.x * 128;   // 0 or 128
  const int m0 = blockIdx.y * 128;
  const int wv = tid >> 6, lane = tid & 63;
  const int cl = lane & 15, bq = lane >> 4;
  const int wm = (wv >> 1) << 6;
  const int wn = (wv & 1) << 6;
  const int sr = tid >> 1, skc = (tid & 1) << 5;
  const unsigned short* asrc = vecp_bf + (size_t)(m0 + sr) * NH + skc;
  const unsigned short* bsrc = wp_bf + (size_t)(n0 + sr) * NH + skc;
  const int sswz = (sr & 15) << 3;
  float4v acc[4][4] = {};
  for (int k0 = 0; k0 < NH; k0 += 64) {
    ushort8v av4[4], bv4[4];
#pragma unroll
    for (int i = 0; i < 4; ++i) av4[i] = *(const ushort8v*)(asrc + k0 + 8 * i);
#pragma unroll
    for (int i = 0; i < 4; ++i) bv4[i] = *(const ushort8v*)(bsrc + k0 + 8 * i);
    __syncthreads();
#pragma unroll
    for (int i = 0; i < 4; ++i) {
      *(ushort8v*)&As[((sr << 6) + skc + 8 * i) ^ sswz] = av4[i];
      *(ushort8v*)&Bs[((sr << 6) + skc + 8 * i) ^ sswz] = bv4[i];
    }
    __syncthreads();
#pragma unroll
    for (int ks = 0; ks < 2; ++ks) {
      const int koff = (ks << 5) + (bq << 3);
      short8v af[4], bf_[4];
#pragma unroll
      for (int mt = 0; mt < 4; ++mt) {
        const int ar = wm + mt * 16 + cl;
        af[mt] = *(const short8v*)&As[((ar << 6) + koff) ^ ((ar & 15) << 3)];
      }
#pragma unroll
      for (int nt = 0; nt < 4; ++nt) {
        const int br = wn + nt * 16 + cl;
        bf_[nt] = *(const short8v*)&Bs[((br << 6) + koff) ^ ((br & 15) << 3)];
      }
#pragma unroll
      for (int mt = 0; mt < 4; ++mt)
#pragma unroll
        for (int nt = 0; nt < 4; ++nt)
          acc[mt][nt] =
              __builtin_amdgcn_mfma_f32_16x16x32_bf16(af[mt], bf_[nt], acc[mt][nt], 0, 0, 0);
    }
  }
#pragma unroll
  for (int mt = 0; mt < 4; ++mt) {
    const int mb = m0 + wm + mt * 16 + (bq << 2);
#pragma unroll
    for (int nt = 0; nt < 4; ++nt) {
      const int n = n0 + wn + nt * 16 + cl;
      if (n < NPV) {
        const float bn = bias[n];
#pragma unroll
        for (int i = 0; i < 4; ++i)
          if (mb + i < 8128)
            out[(size_t)(mb + i) * NPV + n] = acc[mt][nt][i] + bn;
      }
    }
  }
}

extern "C" void kernel_launch(void* const* d_in, const int* in_sizes, int n_in,
                              void* d_out, int out_size, void* d_ws, size_t ws_size,
                              hipStream_t stream) {
  (void)in_sizes; (void)n_in; (void)out_size; (void)ws_size;
  const float* elmo     = (const float*)d_in[0];
  const float* w_ih_f   = (const float*)d_in[1];
  const float* w_hh_f   = (const float*)d_in[2];
  const float* b_f      = (const float*)d_in[3];
  const float* w_ih_b   = (const float*)d_in[4];
  const float* w_hh_b   = (const float*)d_in[5];
  const float* b_b      = (const float*)d_in[6];
  const float* W1       = (const float*)d_in[7];
  const float* W2       = (const float*)d_in[8];
  const float* word_W   = (const float*)d_in[9];
  const float* word_b   = (const float*)d_in[10];
  const float* phrase_W = (const float*)d_in[11];
  const float* phrase_b = (const float*)d_in[12];
  const int* cinfo      = (const int*)d_in[13];
  const int* lab        = (const int*)d_in[15];

  unsigned short* xpb   = (unsigned short*)d_ws;
  float* h_region       = (float*)(xpb + XPB_SZ);   // reused for vecp_bf/wp_bf
  unsigned short* vecp_bf = (unsigned short*)h_region;
  unsigned short* wp_bf   = vecp_bf + VP_SZ;
  float* vec            = h_region + H_SZ;
  unsigned short* h_bf  = (unsigned short*)(vec + VEC_SZ);
  unsigned short* e_bf  = h_bf + HB_SZ;
  unsigned short* W_bf  = e_bf + EB_SZ;
  unsigned short* W12_bf  = W_bf + WB_SZ;
  unsigned short* wout_bf = W12_bf + W12_SZ;
  unsigned short* vec_bf  = wout_bf + WO_SZ;
  int* bar              = (int*)(vec_bf + VB_SZ);

  float* out_word = (float*)d_out;                       // 8192 x 511
  float* out_phr  = out_word + (size_t)8192 * NWV;       // 8128 x 152
  float* out_lw   = out_phr + (size_t)8128 * NPV;        // 8192
  float* out_lp   = out_lw + 8192;                       // 8128

  k_cvt<<<dim3(2048), 256, 0, stream>>>(elmo, w_ih_f, w_ih_b, W1, W2, word_W,
                                        phrase_W, e_bf, W_bf, W12_bf, wout_bf,
                                        wp_bf, bar);
  k_xp<<<dim3(32, 64), 256, 0, stream>>>(e_bf, W_bf, b_f, b_b, xpb);
  k_lstm<<<dim3(32), 256, 0, stream>>>(w_hh_f, w_hh_b, xpb, h_bf, bar);
  k_comb<<<dim3(8, 128), 256, 0, stream>>>(h_bf, W12_bf, vec);
  k_norm<<<dim3(2048), 256, 0, stream>>>(vec, vec_bf);
  k_tail<<<dim3(336), 512, 0, stream>>>(vec, cinfo, vecp_bf, vec_bf, wout_bf,
                                        word_b, out_word, lab, out_lw, out_lp);
  k_outp<<<dim3(2, 64), 256, 0, stream>>>(vecp_bf, wp_bf, phrase_b, out_phr);
}

// Round 18
// 1445.811 us; speedup vs baseline: 1.1998x; 1.1998x over previous
//
#include <hip/hip_runtime.h>
#include <math.h>

// Problem constants
#define NB 64      // batch
#define NS 128     // seq len
#define ND 1024    // input dim
#define NH 512     // hidden
#define NG 2048    // 4*H
#define NTOT 255   // 2S-1
#define NSTEPS 127 // S-1
#define NWV 511
#define NPV 152

static const size_t XPB_SZ = (size_t)2 * NS * NG * NB;
static const size_t H_SZ   = (size_t)2 * NS * NH * NB;   // region reused: vecp_bf + wp_bf
static const size_t VEC_SZ = (size_t)NB * NTOT * NH;
static const size_t HB_SZ  = (size_t)2 * NS * NH * NB;
static const size_t EB_SZ  = (size_t)NB * NS * ND;
static const size_t WB_SZ  = (size_t)4096 * ND;
static const size_t W12_SZ = (size_t)2 * NH * NH;        // 524288
static const size_t WO_SZ  = (size_t)512 * NH;           // 262144 (511 rows + pad)
static const size_t VB_SZ  = (size_t)NB * NS * NH;       // 4194304
static const size_t VP_SZ  = (size_t)8192 * NH;          // 4194304 (8128 + pad)
static const size_t WP_SZ  = (size_t)256 * NH;           // 131072 (152 + pad)
// flag-array barrier: [t<127][dir<2][cb<32] x 32-int (128B) padding
#define BAR_TOT (127 * 2 * 32 * 32)

typedef __attribute__((ext_vector_type(8))) short short8v;
typedef __attribute__((ext_vector_type(8))) unsigned short ushort8v;
typedef __attribute__((ext_vector_type(4))) float float4v;

__device__ __forceinline__ float sigm(float x) { return 1.f / (1.f + __expf(-x)); }
__device__ __forceinline__ float tanh_fast(float x) {
  const float e = __expf(2.f * x);
  return 1.f - 2.f / (e + 1.f);
}
__device__ __forceinline__ unsigned short f2bf(float x) {
  unsigned b = __float_as_uint(x);
  return (unsigned short)((b + 0x7FFFu + ((b >> 16) & 1u)) >> 16);
}
__device__ __forceinline__ float bf2f(unsigned short u) {
  return __uint_as_float(((unsigned)u) << 16);
}

// ---------------- K0: fp32 -> bf16 conversions + barrier zero -------------
__global__ __launch_bounds__(256) void k_cvt(
    const float* __restrict__ elmo, const float* __restrict__ wf,
    const float* __restrict__ wb, const float* __restrict__ W1,
    const float* __restrict__ W2, const float* __restrict__ wordW,
    const float* __restrict__ phraseW,
    unsigned short* __restrict__ elmo_bf, unsigned short* __restrict__ W_bf,
    unsigned short* __restrict__ W12_bf, unsigned short* __restrict__ wout_bf,
    unsigned short* __restrict__ wp_bf, int* __restrict__ bar) {
  const int gid = blockIdx.x * 256 + threadIdx.x;
  if (gid < BAR_TOT) bar[gid] = 0;
  const int NE4 = (NB * NS * ND) / 4;   // 2,097,152
  const int NW4 = (4096 * ND) / 4;      // 1,048,576
  const int NW4h = NW4 / 2;
  const int N12 = (int)(W12_SZ / 4);    // 131,072
  const int NWO = (int)(WO_SZ / 4);     // 65,536
  const int NWO_real = (NWV * NH) / 4;  // 65,408
  const int NP4 = (int)(WP_SZ / 4);     // 32,768
  const int NP4_real = (NPV * NH) / 4;  // 19,456
  const int TOT = NE4 + NW4 + N12 + NWO + NP4;
  for (int i = gid; i < TOT; i += gridDim.x * 256) {
    float4 v = make_float4(0.f, 0.f, 0.f, 0.f);
    unsigned short* dst;
    if (i < NE4) {
      const int e0 = i << 2;
      const int b = e0 >> 17;
      const int t = (e0 >> 10) & 127;
      const int k = e0 & 1023;
      v = *(const float4*)(elmo + e0);
      dst = elmo_bf + ((size_t)((t << 6) + b) << 10) + k;
    } else if (i < NE4 + NW4) {
      const int j = i - NE4;
      v = (j < NW4h) ? *(const float4*)(wf + ((size_t)j << 2))
                     : *(const float4*)(wb + ((size_t)(j - NW4h) << 2));
      dst = W_bf + ((size_t)j << 2);
    } else if (i < NE4 + NW4 + N12) {
      const int j = i - NE4 - NW4;
      const int half = N12 / 2;
      v = (j < half) ? *(const float4*)(W1 + ((size_t)j << 2))
                     : *(const float4*)(W2 + ((size_t)(j - half) << 2));
      dst = W12_bf + ((size_t)j << 2);
    } else if (i < NE4 + NW4 + N12 + NWO) {
      const int j = i - NE4 - NW4 - N12;
      if (j < NWO_real) v = *(const float4*)(wordW + ((size_t)j << 2));
      dst = wout_bf + ((size_t)j << 2);
    } else {
      const int j = i - NE4 - NW4 - N12 - NWO;
      if (j < NP4_real) v = *(const float4*)(phraseW + ((size_t)j << 2));
      dst = wp_bf + ((size_t)j << 2);
    }
    uint2 u;
    u.x = (unsigned)f2bf(v.x) | ((unsigned)f2bf(v.y) << 16);
    u.y = (unsigned)f2bf(v.z) | ((unsigned)f2bf(v.w) << 16);
    *(uint2*)dst = u;
  }
}

// ---------------- K1: xp = elmo @ w_ih^T + bias (bf16 MFMA) ---------------
__global__ __launch_bounds__(256) void k_xp(
    const unsigned short* __restrict__ elmo_bf,
    const unsigned short* __restrict__ W_bf,
    const float* __restrict__ biasf, const float* __restrict__ biasb,
    unsigned short* __restrict__ xpb) {
  __shared__ unsigned short As[128 * 64];
  __shared__ unsigned short Bs[128 * 64];
  const int tid = threadIdx.x;
  const int n0 = blockIdx.x * 128;
  const int m0 = blockIdx.y * 128;
  const int wv = tid >> 6, lane = tid & 63;
  const int cl = lane & 15, bq = lane >> 4;
  const int wm = (wv >> 1) << 6;
  const int wn = (wv & 1) << 6;
  const int sr = tid >> 1, skc = (tid & 1) << 5;
  const unsigned short* asrc = elmo_bf + (size_t)(m0 + sr) * ND + skc;
  const unsigned short* bsrc = W_bf + (size_t)(n0 + sr) * ND + skc;
  const int sswz = (sr & 15) << 3;
  float4v acc[4][4];
#pragma unroll
  for (int nt = 0; nt < 4; ++nt) {
    const int n = n0 + wn + nt * 16 + cl;
    const float bv = (n < 2048) ? biasf[n] : biasb[n - 2048];
#pragma unroll
    for (int mt = 0; mt < 4; ++mt) acc[mt][nt] = (float4v){bv, bv, bv, bv};
  }
  for (int k0 = 0; k0 < ND; k0 += 64) {
    ushort8v av4[4], bv4[4];
#pragma unroll
    for (int i = 0; i < 4; ++i) av4[i] = *(const ushort8v*)(asrc + k0 + 8 * i);
#pragma unroll
    for (int i = 0; i < 4; ++i) bv4[i] = *(const ushort8v*)(bsrc + k0 + 8 * i);
    __syncthreads();
#pragma unroll
    for (int i = 0; i < 4; ++i) {
      *(ushort8v*)&As[((sr << 6) + skc + 8 * i) ^ sswz] = av4[i];
      *(ushort8v*)&Bs[((sr << 6) + skc + 8 * i) ^ sswz] = bv4[i];
    }
    __syncthreads();
#pragma unroll
    for (int ks = 0; ks < 2; ++ks) {
      const int koff = (ks << 5) + (bq << 3);
      short8v af[4], bf_[4];
#pragma unroll
      for (int mt = 0; mt < 4; ++mt) {
        const int ar = wm + mt * 16 + cl;
        af[mt] = *(const short8v*)&As[((ar << 6) + koff) ^ ((ar & 15) << 3)];
      }
#pragma unroll
      for (int nt = 0; nt < 4; ++nt) {
        const int br = wn + nt * 16 + cl;
        bf_[nt] = *(const short8v*)&Bs[((br << 6) + koff) ^ ((br & 15) << 3)];
      }
#pragma unroll
      for (int mt = 0; mt < 4; ++mt)
#pragma unroll
        for (int nt = 0; nt < 4; ++nt)
          acc[mt][nt] =
              __builtin_amdgcn_mfma_f32_16x16x32_bf16(af[mt], bf_[nt], acc[mt][nt], 0, 0, 0);
    }
  }
#pragma unroll
  for (int mt = 0; mt < 4; ++mt) {
    const int mbase = m0 + wm + mt * 16 + (bq << 2);
    const int t = mbase >> 6, b4 = mbase & 63;
#pragma unroll
    for (int nt = 0; nt < 4; ++nt) {
      const int n = n0 + wn + nt * 16 + cl;
      const int dir = n >> 11, grow = n & 2047;
      const int g = grow >> 9, cb = (grow & 511) >> 4;
      const float4v a = acc[mt][nt];
      uint2 u;
      u.x = (unsigned)f2bf(a[0]) | ((unsigned)f2bf(a[1]) << 16);
      u.y = (unsigned)f2bf(a[2]) | ((unsigned)f2bf(a[3]) << 16);
      const size_t idx =
          ((((size_t)(dir * NS + t) * 32 + cb) * 4 + g) << 10) + (cl << 6) + b4;
      *(uint2*)&xpb[idx] = u;
    }
  }
}

// ---------------- K2: persistent BiLSTM scan, v12 (declared floor) --------
// 64 blocks (2 dir x 32 col-blocks of 16) x 256 thr. Full-coverage packed
// h-exchange (256 x 8B SC stores); flag-array barrier; 2-step xp pipeline.
// Five sync variations measured at ~795 us +-5% -> structural floor.
__global__ __launch_bounds__(256) void k_lstm(
    const float* __restrict__ whh_f, const float* __restrict__ whh_b,
    const unsigned short* __restrict__ xpb,
    unsigned short* __restrict__ h_bf, int* __restrict__ bar) {
  __shared__ unsigned short WS[64 * 512];   // 64 KB, swizzled [gr][k]
  __shared__ unsigned short hOut[64 * 16];  // 2 KB bounce [b][col_local]
  const int bid = blockIdx.x;
  const int dir = bid >> 5;
  const int cb = bid & 31;
  const int col0 = cb << 4;
  const int tid = threadIdx.x;
  const int lane = tid & 63;
  const int w = tid >> 6;
  const int cl = lane & 15, bq = lane >> 4;
  const int b4 = (w << 4) + (bq << 2);
  const int arow = (w << 4) + cl;
  const float* whh = dir ? whh_b : whh_f;

  {
    const int gr = tid >> 2;
    const int kc = (tid & 3) << 7;
    const int gg = gr >> 4, cc = gr & 15;
    const float* src = whh + (size_t)(gg * NH + col0 + cc) * NH + kc;
    const int swz = (gr & 15) << 3;
#pragma unroll
    for (int i = 0; i < 16; ++i) {
      const float4 f0 = *(const float4*)(src + 8 * i);
      const float4 f1 = *(const float4*)(src + 8 * i + 4);
      ushort8v u;
      u[0] = f2bf(f0.x); u[1] = f2bf(f0.y); u[2] = f2bf(f0.z); u[3] = f2bf(f0.w);
      u[4] = f2bf(f1.x); u[5] = f2bf(f1.y); u[6] = f2bf(f1.z); u[7] = f2bf(f1.w);
      *(ushort8v*)&WS[((gr << 9) + kc + 8 * i) ^ swz] = u;
    }
  }
  __syncthreads();

  unsigned short* hb_us = h_bf + ((size_t)dir * NS << 15);      // [pos][b][k]
  unsigned long long* hb_ull = (unsigned long long*)h_bf + ((size_t)dir * NS << 12);

  float4v c4 = {0.f, 0.f, 0.f, 0.f};

  // pipeline: xg = xp[t], xn = xp[t+1]; per step prefetch xp[t+2]
  uint2 xg0, xg1, xg2, xg3, xn0, xn1, xn2, xn3;
  {
    const int p0 = dir ? (NS - 1) : 0;
    const unsigned short* xc = xpb + (((size_t)(dir * NS + p0) * 32 + cb) << 12);
    xg0 = *(const uint2*)&xc[(0 << 10) + (cl << 6) + b4];
    xg1 = *(const uint2*)&xc[(1 << 10) + (cl << 6) + b4];
    xg2 = *(const uint2*)&xc[(2 << 10) + (cl << 6) + b4];
    xg3 = *(const uint2*)&xc[(3 << 10) + (cl << 6) + b4];
    const int p1 = dir ? (NS - 2) : 1;
    const unsigned short* xc1 = xpb + (((size_t)(dir * NS + p1) * 32 + cb) << 12);
    xn0 = *(const uint2*)&xc1[(0 << 10) + (cl << 6) + b4];
    xn1 = *(const uint2*)&xc1[(1 << 10) + (cl << 6) + b4];
    xn2 = *(const uint2*)&xc1[(2 << 10) + (cl << 6) + b4];
    xn3 = *(const uint2*)&xc1[(3 << 10) + (cl << 6) + b4];
  }

  for (int t = 0; t < NS; ++t) {
    const int pos = dir ? (NS - 1 - t) : t;
    const int t2 = (t + 2 < NS) ? (t + 2) : (NS - 1);
    const int p2 = dir ? (NS - 1 - t2) : t2;
    const unsigned short* xc2 =
        xpb + (((size_t)(dir * NS + p2) * 32 + cb) << 12);
    const uint2 pf0 = *(const uint2*)&xc2[(0 << 10) + (cl << 6) + b4];
    const uint2 pf1 = *(const uint2*)&xc2[(1 << 10) + (cl << 6) + b4];
    const uint2 pf2 = *(const uint2*)&xc2[(2 << 10) + (cl << 6) + b4];
    const uint2 pf3 = *(const uint2*)&xc2[(3 << 10) + (cl << 6) + b4];

    float4v acc[4] = {{0.f, 0.f, 0.f, 0.f}, {0.f, 0.f, 0.f, 0.f},
                      {0.f, 0.f, 0.f, 0.f}, {0.f, 0.f, 0.f, 0.f}};
    if (t > 0) {
      const int prevpos = dir ? (pos + 1) : (pos - 1);
      const unsigned long long* hsrc = hb_ull + ((size_t)prevpos << 13);
      unsigned long long ha0[16], ha1[16];
#pragma unroll
      for (int ks = 0; ks < 16; ++ks) {
        const int uidx = (arow << 7) + (ks << 3) + (bq << 1);
        ha0[ks] = __hip_atomic_load(&hsrc[uidx], __ATOMIC_RELAXED,
                                    __HIP_MEMORY_SCOPE_AGENT);
        ha1[ks] = __hip_atomic_load(&hsrc[uidx + 1], __ATOMIC_RELAXED,
                                    __HIP_MEMORY_SCOPE_AGENT);
      }
#pragma unroll
      for (int ks = 0; ks < 16; ++ks) {
        union { unsigned long long u[2]; short8v v; } au;
        au.u[0] = ha0[ks]; au.u[1] = ha1[ks];
        const short8v a = au.v;
        const int koff = (ks << 5) + (bq << 3);
#pragma unroll
        for (int g = 0; g < 4; ++g) {
          const short8v bb =
              *(const short8v*)&WS[((((g << 4) + cl) << 9) + koff) ^ (cl << 3)];
          acc[g] = __builtin_amdgcn_mfma_f32_16x16x32_bf16(a, bb, acc[g], 0, 0, 0);
        }
      }
    }
    float hv[4];
#pragma unroll
    for (int i = 0; i < 4; ++i) {
      const unsigned xw0 = (i < 2) ? xg0.x : xg0.y;
      const unsigned xw1 = (i < 2) ? xg1.x : xg1.y;
      const unsigned xw2 = (i < 2) ? xg2.x : xg2.y;
      const unsigned xw3 = (i < 2) ? xg3.x : xg3.y;
      const int sh = (i & 1) << 4;
      const float gi = sigm(acc[0][i] + bf2f((unsigned short)(xw0 >> sh)));
      const float gf = sigm(acc[1][i] + bf2f((unsigned short)(xw1 >> sh)));
      const float gc = tanh_fast(acc[2][i] + bf2f((unsigned short)(xw2 >> sh)));
      const float go = sigm(acc[3][i] + bf2f((unsigned short)(xw3 >> sh)));
      c4[i] = gf * c4[i] + gi * gc;
      hv[i] = go * tanh_fast(c4[i]);
    }
#pragma unroll
    for (int i = 0; i < 4; ++i) hOut[((b4 + i) << 4) + cl] = f2bf(hv[i]);
    __syncthreads();  // hOut visible
    // FULL-coverage packed exchange: 256 threads x 8B (2048B = 64 b x 16 col)
    {
      const int bb = tid >> 2, q = tid & 3;
      const unsigned long long v =
          *(const unsigned long long*)&hOut[(bb << 4) + (q << 2)];
      __hip_atomic_store(
          (unsigned long long*)&hb_us[((size_t)pos << 15) + (bb << 9) + col0 +
                                      (q << 2)],
          v, __ATOMIC_RELAXED, __HIP_MEMORY_SCOPE_AGENT);
    }
    if (t < NS - 1) {
      __syncthreads();  // drains h stores before the flag (release order)
      const int fbase = (((t << 1) + dir) << 5);
      if (tid == 0) {
        __hip_atomic_store(&bar[(size_t)(fbase + cb) << 5], 1,
                           __ATOMIC_RELAXED, __HIP_MEMORY_SCOPE_AGENT);
      }
      if (tid < 64) {
        const size_t fl = (size_t)(fbase + (lane & 31)) << 5;
        while (true) {
          int v = 1;
          if (lane < 32)
            v = __hip_atomic_load(&bar[fl], __ATOMIC_RELAXED,
                                  __HIP_MEMORY_SCOPE_AGENT);
          if (__all(v != 0)) break;
        }
      }
      __syncthreads();
      xg0 = xn0; xg1 = xn1; xg2 = xn2; xg3 = xn3;
      xn0 = pf0; xn1 = pf1; xn2 = pf2; xn3 = pf3;
    }
  }
}

// ---------------- K3: combined = lrelu(fwd@W1^T + bwd@W2^T), bf16 MFMA ----
__global__ __launch_bounds__(256) void k_comb(
    const unsigned short* __restrict__ h_bf,
    const unsigned short* __restrict__ W12_bf, float* __restrict__ vec) {
  __shared__ unsigned short A1s[64 * 128], A2s[64 * 128];
  __shared__ unsigned short B1s[64 * 128], B2s[64 * 128];
  const int tid = threadIdx.x;
  const int n0 = blockIdx.x * 64;
  const int s = blockIdx.y;
  const int w = tid >> 6, lane = tid & 63;
  const int cl = lane & 15, bq = lane >> 4;
  const int wn = w << 4;
  const unsigned short* a1src = h_bf + ((size_t)s << 15);
  const unsigned short* a2src = h_bf + ((size_t)(NS + s) << 15);
  const unsigned short* b1src = W12_bf + (size_t)n0 * NH;
  const unsigned short* b2src = W12_bf + (size_t)(NH + n0) * NH;
  const int srow = tid >> 2, skq = (tid & 3) << 5;
  const int sswz = (srow & 15) << 3;
  float4v acc[4] = {{0.f, 0.f, 0.f, 0.f}, {0.f, 0.f, 0.f, 0.f},
                    {0.f, 0.f, 0.f, 0.f}, {0.f, 0.f, 0.f, 0.f}};
  for (int k0 = 0; k0 < NH; k0 += 128) {
    ushort8v a1[4], a2[4], b1[4], b2[4];
#pragma unroll
    for (int i = 0; i < 4; ++i) {
      const size_t off = (size_t)srow * NH + k0 + skq + 8 * i;
      a1[i] = *(const ushort8v*)(a1src + off);
      a2[i] = *(const ushort8v*)(a2src + off);
      b1[i] = *(const ushort8v*)(b1src + off);
      b2[i] = *(const ushort8v*)(b2src + off);
    }
    __syncthreads();
#pragma unroll
    for (int i = 0; i < 4; ++i) {
      const int idx = ((srow << 7) + skq + 8 * i) ^ sswz;
      *(ushort8v*)&A1s[idx] = a1[i];
      *(ushort8v*)&A2s[idx] = a2[i];
      *(ushort8v*)&B1s[idx] = b1[i];
      *(ushort8v*)&B2s[idx] = b2[i];
    }
    __syncthreads();
#pragma unroll
    for (int ks = 0; ks < 4; ++ks) {
      const int koff = (ks << 5) + (bq << 3);
      const short8v bf1 =
          *(const short8v*)&B1s[(((wn + cl) << 7) + koff) ^ (cl << 3)];
      const short8v bf2 =
          *(const short8v*)&B2s[(((wn + cl) << 7) + koff) ^ (cl << 3)];
#pragma unroll
      for (int mt = 0; mt < 4; ++mt) {
        const int ar = mt * 16 + cl;
        const short8v af1 = *(const short8v*)&A1s[((ar << 7) + koff) ^ (cl << 3)];
        const short8v af2 = *(const short8v*)&A2s[((ar << 7) + koff) ^ (cl << 3)];
        acc[mt] = __builtin_amdgcn_mfma_f32_16x16x32_bf16(af1, bf1, acc[mt], 0, 0, 0);
        acc[mt] = __builtin_amdgcn_mfma_f32_16x16x32_bf16(af2, bf2, acc[mt], 0, 0, 0);
      }
    }
  }
  const int n = n0 + wn + cl;
#pragma unroll
  for (int mt = 0; mt < 4; ++mt) {
    const int b0 = mt * 16 + (bq << 2);
#pragma unroll
    for (int i = 0; i < 4; ++i) {
      float v = acc[mt][i];
      v = v > 0.f ? v : 0.01f * v;
      vec[((size_t)(b0 + i) * NTOT + s) * NH + n] = v;
    }
  }
}

// ---------------- K4: l2-normalize word rows; emit fp32 + bf16 ------------
__global__ __launch_bounds__(256) void k_norm(float* __restrict__ vec,
                                              unsigned short* __restrict__ vec_bf) {
  const int row = (blockIdx.x << 2) + (threadIdx.x >> 6);  // 0..8191
  const int lane = threadIdx.x & 63;
  const int b = row >> 7, s = row & 127;
  float* p = vec + ((size_t)b * NTOT + s) * NH;
  float4 v0 = *(float4*)(p + (lane << 3));
  float4 v1 = *(float4*)(p + (lane << 3) + 4);
  float ss = v0.x * v0.x + v0.y * v0.y + v0.z * v0.z + v0.w * v0.w +
             v1.x * v1.x + v1.y * v1.y + v1.z * v1.z + v1.w * v1.w;
#pragma unroll
  for (int off = 32; off; off >>= 1) ss += __shfl_down(ss, off);
  ss = __shfl(ss, 0);
  const float sc = 1.f / fmaxf(sqrtf(ss), 1e-12f);
  v0.x *= sc; v0.y *= sc; v0.z *= sc; v0.w *= sc;
  v1.x *= sc; v1.y *= sc; v1.z *= sc; v1.w *= sc;
  *(float4*)(p + (lane << 3)) = v0;
  *(float4*)(p + (lane << 3) + 4) = v1;
  ushort8v u;
  u[0] = f2bf(v0.x); u[1] = f2bf(v0.y); u[2] = f2bf(v0.z); u[3] = f2bf(v0.w);
  u[4] = f2bf(v1.x); u[5] = f2bf(v1.y); u[6] = f2bf(v1.z); u[7] = f2bf(v1.w);
  *(ushort8v*)&vec_bf[((size_t)row << 9) + (lane << 3)] = u;
}

// ---------------- K5: fused tail: compose (64) | word GEMM (256) | labels -
// compose v4: sliding-window register rotation (rvd reads per 4-j chunk
// 3 -> 1).
#define SKW(f) ((f) + (((f) >> 5) << 2))
__global__ __launch_bounds__(512) void k_tail(
    float* __restrict__ vec, const int* __restrict__ cinfo,
    unsigned short* __restrict__ vecp_bf,
    const unsigned short* __restrict__ vec_bf,
    const unsigned short* __restrict__ wout_bf,
    const float* __restrict__ wbias, float* __restrict__ out_word,
    const int* __restrict__ lab, float* __restrict__ out_lw,
    float* __restrict__ out_lp) {
  __shared__ float lv[512];
  __shared__ float rvd[1152];
  __shared__ float cpart[8 * 576];
  __shared__ float red[8];
  __shared__ int ciS[NSTEPS * 4];
  __shared__ unsigned short As[128 * 64];
  __shared__ unsigned short Bs[128 * 64];
  const int bid = blockIdx.x;
  const int tid = threadIdx.x;

  if (bid < 64) {
    // ---------------- compose ----------------
    const int b = bid;
    float* vb = vec + (size_t)b * NTOT * NH;
    const int* ib = cinfo + b * NSTEPS * 4;
    for (int idx = tid; idx < NSTEPS * 4; idx += 512) ciS[idx] = ib[idx];
    const int jq = tid >> 6;
    const int jb = jq << 6;
    const int k8 = (tid & 63) << 3;
    const int wid = tid >> 6, lane = tid & 63;
    __syncthreads();
    int p = ciS[1];
    float lvv = vb[(size_t)ciS[2] * NH + tid];
    float rvv = vb[(size_t)ciS[3] * NH + tid];
    for (int i = 0; i < NSTEPS; ++i) {
      lv[tid] = lvv;
      rvd[SKW(tid)] = rvv;
      rvd[SKW(512 + tid)] = rvv;
      __syncthreads();
      float acc[8] = {};
      float4 r0 = *(const float4*)&rvd[SKW(jb + k8)];
      float4 r1 = *(const float4*)&rvd[SKW(jb + k8 + 4)];
#pragma unroll 4
      for (int jj = 0; jj < 64; jj += 4) {
        const int j = jb + jj;
        const float4 l4 = *(const float4*)&lv[j];
        const float4 r2 = *(const float4*)&rvd[SKW(j + k8 + 8)];
        const float rw[12] = {r0.x, r0.y, r0.z, r0.w, r1.x, r1.y,
                              r1.z, r1.w, r2.x, r2.y, r2.z, r2.w};
#pragma unroll
        for (int kk = 0; kk < 8; ++kk)
          acc[kk] += l4.x * rw[kk] + l4.y * rw[kk + 1] + l4.z * rw[kk + 2] +
                     l4.w * rw[kk + 3];
        r0 = r1; r1 = r2;
      }
      const int ca = jq * 576 + SKW(k8);
      *(float4*)&cpart[ca] = make_float4(acc[0], acc[1], acc[2], acc[3]);
      *(float4*)&cpart[ca + 4] = make_float4(acc[4], acc[5], acc[6], acc[7]);
      __syncthreads();
      int pn = 0, ln = 0, rn = 0;
      float lf = 0.f, rf = 0.f;
      const bool more = (i + 1 < NSTEPS);
      if (more) {
        pn = ciS[(i + 1) * 4 + 1];
        ln = ciS[(i + 1) * 4 + 2];
        rn = ciS[(i + 1) * 4 + 3];
        lf = vb[(size_t)ln * NH + tid];
        rf = vb[(size_t)rn * NH + tid];
      }
      float ck = 0.f;
      const int ra = SKW(tid);
#pragma unroll
      for (int q = 0; q < 8; ++q) ck += cpart[q * 576 + ra];
      float ss = ck * ck;
#pragma unroll
      for (int off = 32; off; off >>= 1) ss += __shfl_xor(ss, off);
      if (lane == 0) red[wid] = ss;
      __syncthreads();
      const float tot = red[0] + red[1] + red[2] + red[3] +
                        red[4] + red[5] + red[6] + red[7];
      const float inv = 1.f / fmaxf(sqrtf(tot), 1e-12f);
      const float written = ck * inv;
      vb[(size_t)p * NH + tid] = written;
      vecp_bf[((size_t)b * 127 + (p - NS)) * NH + tid] = f2bf(written);
      if (more) {
        lvv = (ln == p) ? written : lf;
        rvv = (rn == p) ? written : rf;
        p = pn;
      }
      __syncthreads();
    }
  } else if (bid < 320) {
    // ---------------- word output GEMM (512-thread) ----------------
    const int obid = bid - 64;
    const int n0 = (obid & 3) * 128;
    const int m0 = (obid >> 2) * 128;
    const int wv = tid >> 6, lane = tid & 63;
    const int cl = lane & 15, bq = lane >> 4;
    const int wm = (wv >> 2) << 6;
    const int wn = ((wv >> 1) & 1) << 6;
    const int mts = (wv & 1) << 1;   // mt base: 0 or 2
    const int sr = tid >> 2, skc = (tid & 3) << 4;
    const unsigned short* asrc = vec_bf + (size_t)(m0 + sr) * NH + skc;
    const unsigned short* bsrc = wout_bf + (size_t)(n0 + sr) * NH + skc;
    const int sswz = (sr & 15) << 3;
    float4v acc[2][4] = {};
    for (int k0 = 0; k0 < NH; k0 += 64) {
      ushort8v av4[2], bv4[2];
#pragma unroll
      for (int i = 0; i < 2; ++i) av4[i] = *(const ushort8v*)(asrc + k0 + 8 * i);
#pragma unroll
      for (int i = 0; i < 2; ++i) bv4[i] = *(const ushort8v*)(bsrc + k0 + 8 * i);
      __syncthreads();
#pragma unroll
      for (int i = 0; i < 2; ++i) {
        *(ushort8v*)&As[((sr << 6) + skc + 8 * i) ^ sswz] = av4[i];
        *(ushort8v*)&Bs[((sr << 6) + skc + 8 * i) ^ sswz] = bv4[i];
      }
      __syncthreads();
#pragma unroll
      for (int ks = 0; ks < 2; ++ks) {
        const int koff = (ks << 5) + (bq << 3);
        short8v af[2], bf_[4];
#pragma unroll
        for (int mtl = 0; mtl < 2; ++mtl) {
          const int ar = wm + (mts + mtl) * 16 + cl;
          af[mtl] = *(const short8v*)&As[((ar << 6) + koff) ^ ((ar & 15) << 3)];
        }
#pragma unroll
        for (int nt = 0; nt < 4; ++nt) {
          const int br = wn + nt * 16 + cl;
          bf_[nt] = *(const short8v*)&Bs[((br << 6) + koff) ^ ((br & 15) << 3)];
        }
#pragma unroll
        for (int mtl = 0; mtl < 2; ++mtl)
#pragma unroll
          for (int nt = 0; nt < 4; ++nt)
            acc[mtl][nt] = __builtin_amdgcn_mfma_f32_16x16x32_bf16(
                af[mtl], bf_[nt], acc[mtl][nt], 0, 0, 0);
      }
    }
#pragma unroll
    for (int mtl = 0; mtl < 2; ++mtl) {
      const int mb = m0 + wm + (mts + mtl) * 16 + (bq << 2);
#pragma unroll
      for (int nt = 0; nt < 4; ++nt) {
        const int n = n0 + wn + nt * 16 + cl;
        if (n < NWV) {
          const float bn = wbias[n];
#pragma unroll
          for (int i = 0; i < 4; ++i)
            out_word[(size_t)(mb + i) * NWV + n] = acc[mtl][nt][i] + bn;
        }
      }
    }
  } else {
    // ---------------- labels ----------------
    const int i = (bid - 320) * 512 + tid;
    if (i < NB * NS) {
      const int b = i >> 7, s = i & 127;
      out_lw[i] = (float)lab[b * NTOT + s];
    }
    if (i < NB * NSTEPS) {
      const int b = i / 127;
      out_lp[i] = (float)lab[b * NTOT + NS + (i - b * 127)];
    }
  }
}

// ---------------- K6b: phrase output GEMM, bf16 MFMA ----------------------
__global__ __launch_bounds__(256) void k_outp(
    const unsigned short* __restrict__ vecp_bf,
    const unsigned short* __restrict__ wp_bf,
    const float* __restrict__ bias, float* __restrict__ out) {
  __shared__ unsigned short As[128 * 64];
  __shared__ unsigned short Bs[128 * 64];
  const int tid = threadIdx.x;
  const int n0 = blockIdx.x * 128;   // 0 or 128
  const int m0 = blockIdx.y * 128;
  const int wv = tid >> 6, lane = tid & 63;
  const int cl = lane & 15, bq = lane >> 4;
  const int wm = (wv >> 1) << 6;
  const int wn = (wv & 1) << 6;
  const int sr = tid >> 1, skc = (tid & 1) << 5;
  const unsigned short* asrc = vecp_bf + (size_t)(m0 + sr) * NH + skc;
  const unsigned short* bsrc = wp_bf + (size_t)(n0 + sr) * NH + skc;
  const int sswz = (sr & 15) << 3;
  float4v acc[4][4] = {};
  for (int k0 = 0; k0 < NH; k0 += 64) {
    ushort8v av4[4], bv4[4];
#pragma unroll
    for (int i = 0; i < 4; ++i) av4[i] = *(const ushort8v*)(asrc + k0 + 8 * i);
#pragma unroll
    for (int i = 0; i < 4; ++i) bv4[i] = *(const ushort8v*)(bsrc + k0 + 8 * i);
    __syncthreads();
#pragma unroll
    for (int i = 0; i < 4; ++i) {
      *(ushort8v*)&As[((sr << 6) + skc + 8 * i) ^ sswz] = av4[i];
      *(ushort8v*)&Bs[((sr << 6) + skc + 8 * i) ^ sswz] = bv4[i];
    }
    __syncthreads();
#pragma unroll
    for (int ks = 0; ks < 2; ++ks) {
      const int koff = (ks << 5) + (bq << 3);
      short8v af[4], bf_[4];
#pragma unroll
      for (int mt = 0; mt < 4; ++mt) {
        const int ar = wm + mt * 16 + cl;
        af[mt] = *(const short8v*)&As[((ar << 6) + koff) ^ ((ar & 15) << 3)];
      }
#pragma unroll
      for (int nt = 0; nt < 4; ++nt) {
        const int br = wn + nt * 16 + cl;
        bf_[nt] = *(const short8v*)&Bs[((br << 6) + koff) ^ ((br & 15) << 3)];
      }
#pragma unroll
      for (int mt = 0; mt < 4; ++mt)
#pragma unroll
        for (int nt = 0; nt < 4; ++nt)
          acc[mt][nt] =
              __builtin_amdgcn_mfma_f32_16x16x32_bf16(af[mt], bf_[nt], acc[mt][nt], 0, 0, 0);
    }
  }
#pragma unroll
  for (int mt = 0; mt < 4; ++mt) {
    const int mb = m0 + wm + mt * 16 + (bq << 2);
#pragma unroll
    for (int nt = 0; nt < 4; ++nt) {
      const int n = n0 + wn + nt * 16 + cl;
      if (n < NPV) {
        const float bn = bias[n];
#pragma unroll
        for (int i = 0; i < 4; ++i)
          if (mb + i < 8128)
            out[(size_t)(mb + i) * NPV + n] = acc[mt][nt][i] + bn;
      }
    }
  }
}

extern "C" void kernel_launch(void* const* d_in, const int* in_sizes, int n_in,
                              void* d_out, int out_size, void* d_ws, size_t ws_size,
                              hipStream_t stream) {
  (void)in_sizes; (void)n_in; (void)out_size; (void)ws_size;
  const float* elmo     = (const float*)d_in[0];
  const float* w_ih_f   = (const float*)d_in[1];
  const float* w_hh_f   = (const float*)d_in[2];
  const float* b_f      = (const float*)d_in[3];
  const float* w_ih_b   = (const float*)d_in[4];
  const float* w_hh_b   = (const float*)d_in[5];
  const float* b_b      = (const float*)d_in[6];
  const float* W1       = (const float*)d_in[7];
  const float* W2       = (const float*)d_in[8];
  const float* word_W   = (const float*)d_in[9];
  const float* word_b   = (const float*)d_in[10];
  const float* phrase_W = (const float*)d_in[11];
  const float* phrase_b = (const float*)d_in[12];
  const int* cinfo      = (const int*)d_in[13];
  const int* lab        = (const int*)d_in[15];

  unsigned short* xpb   = (unsigned short*)d_ws;
  float* h_region       = (float*)(xpb + XPB_SZ);   // reused for vecp_bf/wp_bf
  unsigned short* vecp_bf = (unsigned short*)h_region;
  unsigned short* wp_bf   = vecp_bf + VP_SZ;
  float* vec            = h_region + H_SZ;
  unsigned short* h_bf  = (unsigned short*)(vec + VEC_SZ);
  unsigned short* e_bf  = h_bf + HB_SZ;
  unsigned short* W_bf  = e_bf + EB_SZ;
  unsigned short* W12_bf  = W_bf + WB_SZ;
  unsigned short* wout_bf = W12_bf + W12_SZ;
  unsigned short* vec_bf  = wout_bf + WO_SZ;
  int* bar              = (int*)(vec_bf + VB_SZ);

  float* out_word = (float*)d_out;                       // 8192 x 511
  float* out_phr  = out_word + (size_t)8192 * NWV;       // 8128 x 152
  float* out_lw   = out_phr + (size_t)8128 * NPV;        // 8192
  float* out_lp   = out_lw + 8192;                       // 8128

  k_cvt<<<dim3(2048), 256, 0, stream>>>(elmo, w_ih_f, w_ih_b, W1, W2, word_W,
                                        phrase_W, e_bf, W_bf, W12_bf, wout_bf,
                                        wp_bf, bar);
  k_xp<<<dim3(32, 64), 256, 0, stream>>>(e_bf, W_bf, b_f, b_b, xpb);
  k_lstm<<<dim3(64), 256, 0, stream>>>(w_hh_f, w_hh_b, xpb, h_bf, bar);
  k_comb<<<dim3(8, 128), 256, 0, stream>>>(h_bf, W12_bf, vec);
  k_norm<<<dim3(2048), 256, 0, stream>>>(vec, vec_bf);
  k_tail<<<dim3(336), 512, 0, stream>>>(vec, cinfo, vecp_bf, vec_bf, wout_bf,
                                        word_b, out_word, lab, out_lw, out_lp);
  k_outp<<<dim3(2, 64), 256, 0, stream>>>(vecp_bf, wp_bf, phrase_b, out_phr);
}